// Round 14
// baseline (257.080 us; speedup 1.0000x reference)
//
#include <hip/hip_runtime.h>
#include <math.h>

constexpr int NN  = 100000;   // nodes
constexpr int NE  = 1600000;  // edges
constexpr int DIM = 128;
constexpr int NBUCK = (NN + 255) / 256;      // 391 dst-buckets
constexpr int CAP  = 4608;                   // per-bucket segment capacity

typedef unsigned short ushort;
typedef unsigned int uint;
typedef __attribute__((ext_vector_type(8))) short bf16x8;
typedef __attribute__((ext_vector_type(4))) float f32x4;
typedef __attribute__((ext_vector_type(4))) uint uint4v;

// ---- workspace layout (bytes) ----
constexpr size_t OFF_GCUR   = 0;                          // int[NBUCK]
constexpr size_t OFF_ROWB   = 2048;                       // int[NN]
constexpr size_t OFF_ROWE   = OFF_ROWB + 400128;          // int[NN]
constexpr size_t OFF_COL    = OFF_ROWE + 400128;          // int[NBUCK*CAP]
constexpr size_t OFF_TMP    = OFF_COL  + 7206912;         // uint[NBUCK*CAP]
constexpr size_t OFF_WT     = OFF_TMP  + 7206912;         // 4 x 128x128 bf16
constexpr size_t OFF_XB     = OFF_WT   + 131072;          // bf16[NN*128]
constexpr size_t OFF_HB     = OFF_XB   + 25600000;        // bf16[NN*128]
constexpr size_t OFF_MB     = OFF_HB   + 25600000;        // bf16[NN*128]
// total ≈ 92.1 MB

__device__ __forceinline__ int eidx(const void* p, int is64, long long i) {
  return is64 ? (int)((const long long*)p)[i] : ((const int*)p)[i];
}

__device__ __forceinline__ ushort f2b(float f) {  // fp32 -> bf16 RNE
  uint u = __float_as_uint(f);
  return (ushort)((u + 0x7FFFu + ((u >> 16) & 1u)) >> 16);
}
__device__ __forceinline__ float blo(uint u) { return __uint_as_float(u << 16); }
__device__ __forceinline__ float bhi(uint u) { return __uint_as_float(u & 0xFFFF0000u); }

// block-uniform int64-vs-int32 detect (deterministic across blocks)
__device__ __forceinline__ int detect64(const void* e) {
  __shared__ int f;
  if (threadIdx.x == 0) f = 0;
  __syncthreads();
  const uint* u = (const uint*)e;
  uint v = 0;
  for (int i = threadIdx.x; i < 4096; i += blockDim.x) v |= u[2 * i + 1];
  if (v) atomicOr(&f, 1);
  __syncthreads();
  return f == 0;  // all-high-words-zero -> int64
}

// LDS multisplit: group edges by dst-bucket into tmp with full-line flushes.
// packed entry = (src << 8) | (dst & 255)
__global__ __launch_bounds__(256) void k_bin(const void* e, int* gcur,
                                             uint* tmp) {
  __shared__ uint buf[NBUCK * 32];
  __shared__ int cnt[NBUCK];
  int is64 = detect64(e);
  for (int b = threadIdx.x; b < NBUCK; b += 256) cnt[b] = 0;
  __syncthreads();

  for (int base = blockIdx.x * 256; base < NE; base += gridDim.x * 256) {
    int i = base + threadIdx.x;
    if (i < NE) {
      int src = eidx(e, is64, i);
      int dst = eidx(e, is64, (long long)NE + i);
      int b = dst >> 8;
      uint pack = ((uint)src << 8) | (uint)(dst & 255);
      int c = atomicAdd(&cnt[b], 1);
      if (c < 32) {
        buf[b * 32 + c] = pack;
      } else {  // overflow (pathological skew) - direct fragmented store
        int p = atomicAdd(&gcur[b], 1);
        tmp[p] = pack;
      }
    }
    __syncthreads();
    // flush full 64B lines, one thread per bucket
    for (int b = threadIdx.x; b < NBUCK; b += 256) {
      int c = min(cnt[b], 32);
      if (c >= 16) {
        int gpos = atomicAdd(&gcur[b], 16);
        uint* s = &buf[b * 32];
#pragma unroll
        for (int q = 0; q < 4; q++) {
          uint4 v = {s[q * 4 + 0], s[q * 4 + 1], s[q * 4 + 2], s[q * 4 + 3]};
          *(uint4*)(tmp + gpos + q * 4) = v;
        }
        int rem = c - 16;
        for (int q = 0; q < rem; q++) s[q] = s[16 + q];
        cnt[b] = rem;
      } else {
        cnt[b] = c;
      }
    }
    __syncthreads();
  }
  // final residual flush
  for (int b = threadIdx.x; b < NBUCK; b += 256) {
    int c = cnt[b];
    if (c > 0) {
      int gpos = atomicAdd(&gcur[b], c);
      for (int q = 0; q < c; q++) tmp[gpos + q] = buf[b * 32 + q];
    }
  }
}

// one workgroup per bucket: count node degrees from tmp segment, block-scan
// into rowbeg/rowend (coalesced), then order tmp into final col layout.
__global__ __launch_bounds__(256) void k_reorder(const uint* __restrict__ tmp,
                                                 const int* __restrict__ gcur,
                                                 int* __restrict__ rowbeg,
                                                 int* __restrict__ rowend,
                                                 int* __restrict__ col) {
  __shared__ int cnt[256];
  __shared__ int lcur[256];
  __shared__ int wsum[4];
  int b = blockIdx.x;
  int t = threadIdx.x;
  int segBeg = b * CAP;
  int segEnd = gcur[b];
  cnt[t] = 0;
  __syncthreads();
  // pass A: degree count
  for (int j = segBeg + t; j < segEnd; j += 256)
    atomicAdd(&cnt[tmp[j] & 255], 1);
  __syncthreads();
  // block exclusive scan of 256 counts
  int c = cnt[t];
  int lane = t & 63, wid = t >> 6;
  int s = c;
#pragma unroll
  for (int off = 1; off < 64; off <<= 1) {
    int v = __shfl_up(s, off, 64);
    if (lane >= off) s += v;
  }
  if (lane == 63) wsum[wid] = s;
  __syncthreads();
  if (t == 0) {
    int r0 = wsum[0], r1 = wsum[1], r2 = wsum[2];
    wsum[1] = r0;
    wsum[2] = r0 + r1;
    wsum[3] = r0 + r1 + r2;
    wsum[0] = 0;
  }
  __syncthreads();
  int excl = s - c + wsum[wid];
  int node = (b << 8) + t;
  if (node < NN) {
    rowbeg[node] = segBeg + excl;
    rowend[node] = segBeg + excl + c;
  }
  lcur[t] = segBeg + excl;
  __syncthreads();
  // pass B: scatter into col
  for (int j = segBeg + t; j < segEnd; j += 256) {
    uint p = tmp[j];
    int pos = atomicAdd(&lcur[p & 255], 1);
    col[pos] = (int)(p >> 8);
  }
}

// x fp32 -> bf16 (blocks 0..12499), weight transpose+cvt (12500..12755),
// gcur seed (block 12756, strided over all NBUCK).
__global__ void k_cvtall(const float* __restrict__ x, ushort* __restrict__ xb,
                         const float* __restrict__ W1l, const float* __restrict__ W1r,
                         const float* __restrict__ W2l, const float* __restrict__ W2r,
                         ushort* __restrict__ WT, int* __restrict__ gcur) {
  int b = blockIdx.x;
  if (b < 12500) {
    int i = b * 256 + threadIdx.x;  // one float4 each
    float4 v = ((const float4*)x)[i];
    ushort4 o = {f2b(v.x), f2b(v.y), f2b(v.z), f2b(v.w)};
    ((ushort4*)xb)[i] = o;
  } else if (b < 12756) {
    int id = (b - 12500) * 256 + threadIdx.x;  // 65536 total
    int m = id >> 14, idx = id & 16383;
    int k = idx >> 7, n = idx & 127;
    const float* W = (m == 0) ? W1l : (m == 1) ? W1r : (m == 2) ? W2l : W2r;
    WT[m * 16384 + n * 128 + k] = f2b(W[k * 128 + n]);
  } else {
    for (int i = threadIdx.x; i < NBUCK; i += 256) gcur[i] = i * CAP;
  }
}

#define ACC8(P, U)                                         \
  P[0] += blo(U.x); P[1] += bhi(U.x);                      \
  P[2] += blo(U.y); P[3] += bhi(U.y);                      \
  P[4] += blo(U.z); P[5] += bhi(U.z);                      \
  P[6] += blo(U.w); P[7] += bhi(U.w);

// One wave per node. uint4-per-lane: 16 lanes cover a 256B row, 4 edge-groups
// process 4 edges per load instruction; cross-group shfl reduce.
__global__ void k_agg(const ushort* __restrict__ feat,
                      const int* __restrict__ rowbeg,
                      const int* __restrict__ rowend,
                      const int* __restrict__ col,
                      ushort* __restrict__ out) {
  int gtid = blockIdx.x * blockDim.x + threadIdx.x;
  int v = gtid >> 6;
  int lane = gtid & 63;
  if (v >= NN) return;
  int beg = rowbeg[v], end = rowend[v];
  int g = lane >> 4;   // edge group 0..3
  int q = lane & 15;   // 16B slot within row
  const uint4v* F4 = (const uint4v*)feat;
  float p[8] = {0.f, 0.f, 0.f, 0.f, 0.f, 0.f, 0.f, 0.f};
  int j = beg;
  for (; j + 15 < end; j += 16) {  // 4 independent 1KB loads in flight
    int c0 = __builtin_nontemporal_load(&col[j + g]);
    int c1 = __builtin_nontemporal_load(&col[j + 4 + g]);
    int c2 = __builtin_nontemporal_load(&col[j + 8 + g]);
    int c3 = __builtin_nontemporal_load(&col[j + 12 + g]);
    uint4v u0 = F4[(size_t)c0 * 16 + q];
    uint4v u1 = F4[(size_t)c1 * 16 + q];
    uint4v u2 = F4[(size_t)c2 * 16 + q];
    uint4v u3 = F4[(size_t)c3 * 16 + q];
    ACC8(p, u0)
    ACC8(p, u1)
    ACC8(p, u2)
    ACC8(p, u3)
  }
  for (; j + 3 < end; j += 4) {
    int c0 = __builtin_nontemporal_load(&col[j + g]);
    uint4v u0 = F4[(size_t)c0 * 16 + q];
    ACC8(p, u0)
  }
  int rem = end - j;
  if (g < rem) {
    int c0 = __builtin_nontemporal_load(&col[j + g]);
    uint4v u0 = F4[(size_t)c0 * 16 + q];
    ACC8(p, u0)
  }
  // reduce across the 4 groups
#pragma unroll
  for (int k = 0; k < 8; k++) {
    p[k] += __shfl_xor(p[k], 16, 64);
    p[k] += __shfl_xor(p[k], 32, 64);
  }
  float inv = 1.0f / (float)max(end - beg, 1);
  if (g == 0) {
    uint4v o;
    o.x = (uint)f2b(p[0] * inv) | ((uint)f2b(p[1] * inv) << 16);
    o.y = (uint)f2b(p[2] * inv) | ((uint)f2b(p[3] * inv) << 16);
    o.z = (uint)f2b(p[4] * inv) | ((uint)f2b(p[5] * inv) << 16);
    o.w = (uint)f2b(p[6] * inv) | ((uint)f2b(p[7] * inv) << 16);
    __builtin_nontemporal_store(o, &((uint4v*)out)[(size_t)v * 16 + q]);
  }
}

// MFMA GEMM: 128-row blocks, 8 waves, BOTH W matrices staged into 64KB LDS
// once (read-order-contiguous layout), single barrier, then barrier-free
// MFMA + epilogue per wave.
template <int MODE>
__global__ __launch_bounds__(512) void k_mm(
    const ushort* __restrict__ A1, const ushort* __restrict__ A2,
    const ushort* __restrict__ B1t, const ushort* __restrict__ B2t,
    const float* __restrict__ bias, void* __restrict__ outp,
    const float* __restrict__ Wp, const float* __restrict__ bp,
    const float* __restrict__ Wd, const float* __restrict__ bd) {
  __shared__ ushort Bs[2][128 * 128];  // 64KB
  int tid = threadIdx.x;
  int wid = tid >> 6, lane = tid & 63;
  int row0 = blockIdx.x * 128 + wid * 16;
  int r = lane & 15, kg = lane >> 4;

  int arow = row0 + r;
  bool aok = arow < NN;
  const ushort* Ar1 = A1 + (size_t)arow * DIM + kg * 8;
  const ushort* Ar2 = A2 + (size_t)arow * DIM + kg * 8;

  // prefetch all A fragments (8 loads in flight across staging)
  bf16x8 a[2][4];
#pragma unroll
  for (int ks = 0; ks < 4; ks++)
    a[0][ks] = aok ? *(const bf16x8*)(Ar1 + ks * 32)
                   : (bf16x8){0, 0, 0, 0, 0, 0, 0, 0};
#pragma unroll
  for (int ks = 0; ks < 4; ks++)
    a[1][ks] = aok ? *(const bf16x8*)(Ar2 + ks * 32)
                   : (bf16x8){0, 0, 0, 0, 0, 0, 0, 0};

  // stage both matrices: 4096 chunks of 16B, thread covers {i*512 + tid}
#pragma unroll
  for (int i = 0; i < 8; i++) {
    int phys = i * 512 + tid;
    int half = phys >> 11;           // 0: W_l, 1: W_r
    int ph = phys & 2047;
    int pr = ph & 15, pkg = (ph >> 4) & 3;
    int pf = (ph >> 6) & 7, pks = (ph >> 9) & 3;
    int gchunk = (pf * 16 + pr) * 16 + pks * 4 + pkg;
    const ushort* Bt = half ? B2t : B1t;
    ((uint4*)Bs)[phys] = ((const uint4*)Bt)[gchunk];
  }
  __syncthreads();

  f32x4 acc[8];
#pragma unroll
  for (int f = 0; f < 8; f++) acc[f] = (f32x4){0.f, 0.f, 0.f, 0.f};

#pragma unroll
  for (int half = 0; half < 2; half++) {
#pragma unroll
    for (int ks = 0; ks < 4; ks++) {
#pragma unroll
      for (int f = 0; f < 8; f++) {
        bf16x8 b = *(const bf16x8*)&Bs[half][(ks * 512 + f * 64 + lane) * 8];
        acc[f] = __builtin_amdgcn_mfma_f32_16x16x32_bf16(a[half][ks], b, acc[f],
                                                         0, 0, 0);
      }
    }
  }

  if (MODE == 0) {
    ushort* O = (ushort*)outp;
#pragma unroll
    for (int rr = 0; rr < 4; rr++) {
      int orow = row0 + kg * 4 + rr;
      if (orow < NN) {
#pragma unroll
        for (int f = 0; f < 8; f++) {
          int n = f * 16 + r;
          float h = fmaxf(acc[f][rr] + bias[n], 0.f);
          O[(size_t)orow * DIM + n] = f2b(h);
        }
      }
    }
  } else {
    float* O = (float*)outp;
    float bpv = bp[0], bdv = bd[0];
#pragma unroll
    for (int rr = 0; rr < 4; rr++) {
      float p = 0.f, dv = 0.f;
#pragma unroll
      for (int f = 0; f < 8; f++) {
        int n = f * 16 + r;
        float h = fmaxf(acc[f][rr] + bias[n], 0.f);
        p += h * Wp[n];
        dv += h * Wd[n];
      }
#pragma unroll
      for (int m = 1; m < 16; m <<= 1) {
        p += __shfl_xor(p, m, 64);
        dv += __shfl_xor(dv, m, 64);
      }
      int orow = row0 + kg * 4 + rr;
      if (r == 0 && orow < NN) {
        float preds = p + bpv;
        float diffs = 1.f / (1.f + expf(-(dv + bdv)));
        O[orow] = preds - diffs;
        O[NN + orow] = preds + diffs;
      }
    }
  }
}

extern "C" void kernel_launch(void* const* d_in, const int* in_sizes, int n_in,
                              void* d_out, int out_size, void* d_ws, size_t ws_size,
                              hipStream_t stream) {
  const float* x   = (const float*)d_in[0];
  const void*  ei  = d_in[1];
  const float* W1l = (const float*)d_in[2];
  const float* b1  = (const float*)d_in[3];
  const float* W1r = (const float*)d_in[4];
  const float* W2l = (const float*)d_in[5];
  const float* b2  = (const float*)d_in[6];
  const float* W2r = (const float*)d_in[7];
  const float* Wp  = (const float*)d_in[8];
  const float* bp  = (const float*)d_in[9];
  const float* Wd  = (const float*)d_in[10];
  const float* bd  = (const float*)d_in[11];

  char* ws = (char*)d_ws;
  int* gcur   = (int*)(ws + OFF_GCUR);
  int* rowbeg = (int*)(ws + OFF_ROWB);
  int* rowend = (int*)(ws + OFF_ROWE);
  int* col    = (int*)(ws + OFF_COL);
  uint* tmp   = (uint*)(ws + OFF_TMP);
  ushort* WT  = (ushort*)(ws + OFF_WT);
  ushort* Xb  = (ushort*)(ws + OFF_XB);
  ushort* Hb  = (ushort*)(ws + OFF_HB);
  ushort* Mb  = (ushort*)(ws + OFF_MB);

  k_cvtall<<<12757, 256, 0, stream>>>(x, Xb, W1l, W1r, W2l, W2r, WT, gcur);
  k_bin<<<256, 256, 0, stream>>>(ei, gcur, tmp);
  k_reorder<<<NBUCK, 256, 0, stream>>>(tmp, gcur, rowbeg, rowend, col);

  // layer 1
  k_agg<<<(NN * 64 + 255) / 256, 256, 0, stream>>>(Xb, rowbeg, rowend, col, Mb);
  k_mm<0><<<(NN + 127) / 128, 512, 0, stream>>>(Mb, Xb, WT, WT + 16384, b1, Hb,
                                                nullptr, nullptr, nullptr, nullptr);
  // layer 2 + heads
  k_agg<<<(NN * 64 + 255) / 256, 256, 0, stream>>>(Hb, rowbeg, rowend, col, Mb);
  k_mm<1><<<(NN + 127) / 128, 512, 0, stream>>>(Mb, Hb, WT + 32768, WT + 49152, b2,
                                                d_out, Wp, bp, Wd, bd);
}

// Round 15
// 237.523 us; speedup vs baseline: 1.0823x; 1.0823x over previous
//
#include <hip/hip_runtime.h>
#include <math.h>

constexpr int NN  = 100000;   // nodes
constexpr int NE  = 1600000;  // edges
constexpr int DIM = 128;
constexpr int NBUCK = (NN + 255) / 256;      // 391 dst-buckets
constexpr int CAP  = 4608;                   // per-bucket segment capacity

typedef unsigned short ushort;
typedef unsigned int uint;
typedef __attribute__((ext_vector_type(8))) short bf16x8;
typedef __attribute__((ext_vector_type(4))) float f32x4;
typedef __attribute__((ext_vector_type(4))) uint uint4v;

// ---- workspace layout (bytes) ----
constexpr size_t OFF_GCUR   = 0;                          // int[NBUCK]
constexpr size_t OFF_ROWB   = 2048;                       // int[NN]
constexpr size_t OFF_ROWE   = OFF_ROWB + 400128;          // int[NN]
constexpr size_t OFF_COL    = OFF_ROWE + 400128;          // int[NBUCK*CAP]
constexpr size_t OFF_TMP    = OFF_COL  + 7206912;         // uint[NBUCK*CAP]
constexpr size_t OFF_WT     = OFF_TMP  + 7206912;         // 4 x 128x128 bf16 (phys order)
constexpr size_t OFF_XB     = OFF_WT   + 131072;          // bf16[NN*128]
constexpr size_t OFF_HB     = OFF_XB   + 25600000;        // bf16[NN*128]
constexpr size_t OFF_MB     = OFF_HB   + 25600000;        // bf16[NN*128]
// total ≈ 92.1 MB

__device__ __forceinline__ int eidx(const void* p, int is64, long long i) {
  return is64 ? (int)((const long long*)p)[i] : ((const int*)p)[i];
}

__device__ __forceinline__ ushort f2b(float f) {  // fp32 -> bf16 RNE
  uint u = __float_as_uint(f);
  return (ushort)((u + 0x7FFFu + ((u >> 16) & 1u)) >> 16);
}
__device__ __forceinline__ float blo(uint u) { return __uint_as_float(u << 16); }
__device__ __forceinline__ float bhi(uint u) { return __uint_as_float(u & 0xFFFF0000u); }

// block-uniform int64-vs-int32 detect (deterministic across blocks)
__device__ __forceinline__ int detect64(const void* e) {
  __shared__ int f;
  if (threadIdx.x == 0) f = 0;
  __syncthreads();
  const uint* u = (const uint*)e;
  uint v = 0;
  for (int i = threadIdx.x; i < 4096; i += blockDim.x) v |= u[2 * i + 1];
  if (v) atomicOr(&f, 1);
  __syncthreads();
  return f == 0;  // all-high-words-zero -> int64
}

// LDS multisplit: group edges by dst-bucket into tmp with full-line flushes.
// packed entry = (src << 8) | (dst & 255)
__global__ __launch_bounds__(256) void k_bin(const void* e, int* gcur,
                                             uint* tmp) {
  __shared__ uint buf[NBUCK * 32];
  __shared__ int cnt[NBUCK];
  int is64 = detect64(e);
  for (int b = threadIdx.x; b < NBUCK; b += 256) cnt[b] = 0;
  __syncthreads();

  for (int base = blockIdx.x * 256; base < NE; base += gridDim.x * 256) {
    int i = base + threadIdx.x;
    if (i < NE) {
      int src = eidx(e, is64, i);
      int dst = eidx(e, is64, (long long)NE + i);
      int b = dst >> 8;
      uint pack = ((uint)src << 8) | (uint)(dst & 255);
      int c = atomicAdd(&cnt[b], 1);
      if (c < 32) {
        buf[b * 32 + c] = pack;
      } else {  // overflow (pathological skew) - direct fragmented store
        int p = atomicAdd(&gcur[b], 1);
        tmp[p] = pack;
      }
    }
    __syncthreads();
    // flush full 64B lines, one thread per bucket
    for (int b = threadIdx.x; b < NBUCK; b += 256) {
      int c = min(cnt[b], 32);
      if (c >= 16) {
        int gpos = atomicAdd(&gcur[b], 16);
        uint* s = &buf[b * 32];
#pragma unroll
        for (int q = 0; q < 4; q++) {
          uint4 v = {s[q * 4 + 0], s[q * 4 + 1], s[q * 4 + 2], s[q * 4 + 3]};
          *(uint4*)(tmp + gpos + q * 4) = v;
        }
        int rem = c - 16;
        for (int q = 0; q < rem; q++) s[q] = s[16 + q];
        cnt[b] = rem;
      } else {
        cnt[b] = c;
      }
    }
    __syncthreads();
  }
  // final residual flush
  for (int b = threadIdx.x; b < NBUCK; b += 256) {
    int c = cnt[b];
    if (c > 0) {
      int gpos = atomicAdd(&gcur[b], c);
      for (int q = 0; q < c; q++) tmp[gpos + q] = buf[b * 32 + q];
    }
  }
}

// one workgroup per bucket: count node degrees from tmp segment, block-scan
// into rowbeg/rowend (coalesced), then order tmp into final col layout.
__global__ __launch_bounds__(256) void k_reorder(const uint* __restrict__ tmp,
                                                 const int* __restrict__ gcur,
                                                 int* __restrict__ rowbeg,
                                                 int* __restrict__ rowend,
                                                 int* __restrict__ col) {
  __shared__ int cnt[256];
  __shared__ int lcur[256];
  __shared__ int wsum[4];
  int b = blockIdx.x;
  int t = threadIdx.x;
  int segBeg = b * CAP;
  int segEnd = gcur[b];
  cnt[t] = 0;
  __syncthreads();
  // pass A: degree count
  for (int j = segBeg + t; j < segEnd; j += 256)
    atomicAdd(&cnt[tmp[j] & 255], 1);
  __syncthreads();
  // block exclusive scan of 256 counts
  int c = cnt[t];
  int lane = t & 63, wid = t >> 6;
  int s = c;
#pragma unroll
  for (int off = 1; off < 64; off <<= 1) {
    int v = __shfl_up(s, off, 64);
    if (lane >= off) s += v;
  }
  if (lane == 63) wsum[wid] = s;
  __syncthreads();
  if (t == 0) {
    int r0 = wsum[0], r1 = wsum[1], r2 = wsum[2];
    wsum[1] = r0;
    wsum[2] = r0 + r1;
    wsum[3] = r0 + r1 + r2;
    wsum[0] = 0;
  }
  __syncthreads();
  int excl = s - c + wsum[wid];
  int node = (b << 8) + t;
  if (node < NN) {
    rowbeg[node] = segBeg + excl;
    rowend[node] = segBeg + excl + c;
  }
  lcur[t] = segBeg + excl;
  __syncthreads();
  // pass B: scatter into col
  for (int j = segBeg + t; j < segEnd; j += 256) {
    uint p = tmp[j];
    int pos = atomicAdd(&lcur[p & 255], 1);
    col[pos] = (int)(p >> 8);
  }
}

// x fp32 -> bf16 (blocks 0..12499), weight cvt into PHYS-LINEAR layout
// (12500..12755), gcur seed (block 12756).
// phys layout (per matrix, 2048 16B-chunks): chunk = ks*512 + f*64 + kg*16 + r,
// element e: holds W[k][n] with n = f*16+r, k = (ks*4+kg)*8 + e. k_mm then
// stages LDS with a pure linear copy (coalesced + conflict-free).
__global__ void k_cvtall(const float* __restrict__ x, ushort* __restrict__ xb,
                         const float* __restrict__ W1l, const float* __restrict__ W1r,
                         const float* __restrict__ W2l, const float* __restrict__ W2r,
                         ushort* __restrict__ WT, int* __restrict__ gcur) {
  int b = blockIdx.x;
  if (b < 12500) {
    int i = b * 256 + threadIdx.x;  // one float4 each
    float4 v = ((const float4*)x)[i];
    ushort4 o = {f2b(v.x), f2b(v.y), f2b(v.z), f2b(v.w)};
    ((ushort4*)xb)[i] = o;
  } else if (b < 12756) {
    int id = (b - 12500) * 256 + threadIdx.x;  // 65536 total
    int m = id >> 14;        // matrix 0..3
    int h = id & 16383;      // halfword index within matrix (phys*8 + e)
    int e = h & 7;
    int phys = h >> 3;
    int r = phys & 15, kg = (phys >> 4) & 3;
    int f = (phys >> 6) & 7, ks = phys >> 9;
    int n = f * 16 + r;
    int k = (ks * 4 + kg) * 8 + e;
    const float* W = (m == 0) ? W1l : (m == 1) ? W1r : (m == 2) ? W2l : W2r;
    WT[m * 16384 + h] = f2b(W[k * 128 + n]);
  } else {
    for (int i = threadIdx.x; i < NBUCK; i += 256) gcur[i] = i * CAP;
  }
}

#define ACC8(P, U)                                         \
  P[0] += blo(U.x); P[1] += bhi(U.x);                      \
  P[2] += blo(U.y); P[3] += bhi(U.y);                      \
  P[4] += blo(U.z); P[5] += bhi(U.z);                      \
  P[6] += blo(U.w); P[7] += bhi(U.w);

// One wave per node. uint4-per-lane: 16 lanes cover a 256B row, 4 edge-groups
// process 4 edges per load instruction. Tail handled by one predicated
// 4-load step (clamped index + select-to-zero) -> always 4 loads deep.
__global__ void k_agg(const ushort* __restrict__ feat,
                      const int* __restrict__ rowbeg,
                      const int* __restrict__ rowend,
                      const int* __restrict__ col,
                      ushort* __restrict__ out) {
  int gtid = blockIdx.x * blockDim.x + threadIdx.x;
  int v = gtid >> 6;
  int lane = gtid & 63;
  if (v >= NN) return;
  int beg = rowbeg[v], end = rowend[v];
  int g = lane >> 4;   // edge group 0..3
  int q = lane & 15;   // 16B slot within row
  const uint4v* F4 = (const uint4v*)feat;
  float p[8] = {0.f, 0.f, 0.f, 0.f, 0.f, 0.f, 0.f, 0.f};
  int j = beg;
  for (; j + 15 < end; j += 16) {  // 4 independent 1KB loads in flight
    int c0 = __builtin_nontemporal_load(&col[j + g]);
    int c1 = __builtin_nontemporal_load(&col[j + 4 + g]);
    int c2 = __builtin_nontemporal_load(&col[j + 8 + g]);
    int c3 = __builtin_nontemporal_load(&col[j + 12 + g]);
    uint4v u0 = F4[(size_t)c0 * 16 + q];
    uint4v u1 = F4[(size_t)c1 * 16 + q];
    uint4v u2 = F4[(size_t)c2 * 16 + q];
    uint4v u3 = F4[(size_t)c3 * 16 + q];
    ACC8(p, u0)
    ACC8(p, u1)
    ACC8(p, u2)
    ACC8(p, u3)
  }
  if (j < end) {  // predicated tail: up to 15 edges, still 4 loads deep
    int last = end - 1;
    int i0 = j + g, i1 = j + 4 + g, i2 = j + 8 + g, i3 = j + 12 + g;
    int c0 = __builtin_nontemporal_load(&col[min(i0, last)]);
    int c1 = __builtin_nontemporal_load(&col[min(i1, last)]);
    int c2 = __builtin_nontemporal_load(&col[min(i2, last)]);
    int c3 = __builtin_nontemporal_load(&col[min(i3, last)]);
    uint4v u0 = F4[(size_t)c0 * 16 + q];
    uint4v u1 = F4[(size_t)c1 * 16 + q];
    uint4v u2 = F4[(size_t)c2 * 16 + q];
    uint4v u3 = F4[(size_t)c3 * 16 + q];
    uint4v z = {0, 0, 0, 0};
    if (i0 > last) u0 = z;
    if (i1 > last) u1 = z;
    if (i2 > last) u2 = z;
    if (i3 > last) u3 = z;
    ACC8(p, u0)
    ACC8(p, u1)
    ACC8(p, u2)
    ACC8(p, u3)
  }
  // reduce across the 4 groups
#pragma unroll
  for (int k = 0; k < 8; k++) {
    p[k] += __shfl_xor(p[k], 16, 64);
    p[k] += __shfl_xor(p[k], 32, 64);
  }
  float inv = 1.0f / (float)max(end - beg, 1);
  if (g == 0) {
    uint4v o;
    o.x = (uint)f2b(p[0] * inv) | ((uint)f2b(p[1] * inv) << 16);
    o.y = (uint)f2b(p[2] * inv) | ((uint)f2b(p[3] * inv) << 16);
    o.z = (uint)f2b(p[4] * inv) | ((uint)f2b(p[5] * inv) << 16);
    o.w = (uint)f2b(p[6] * inv) | ((uint)f2b(p[7] * inv) << 16);
    __builtin_nontemporal_store(o, &((uint4v*)out)[(size_t)v * 16 + q]);
  }
}

// MFMA GEMM: 128-row blocks, 8 waves, BOTH W matrices staged into 64KB LDS
// via pure linear copy (WT already in phys order), single barrier, then
// barrier-free MFMA + epilogue per wave.
template <int MODE>
__global__ __launch_bounds__(512) void k_mm(
    const ushort* __restrict__ A1, const ushort* __restrict__ A2,
    const ushort* __restrict__ B1t, const ushort* __restrict__ B2t,
    const float* __restrict__ bias, void* __restrict__ outp,
    const float* __restrict__ Wp, const float* __restrict__ bp,
    const float* __restrict__ Wd, const float* __restrict__ bd) {
  __shared__ ushort Bs[2][128 * 128];  // 64KB
  int tid = threadIdx.x;
  int wid = tid >> 6, lane = tid & 63;
  int row0 = blockIdx.x * 128 + wid * 16;
  int r = lane & 15, kg = lane >> 4;

  int arow = row0 + r;
  bool aok = arow < NN;
  const ushort* Ar1 = A1 + (size_t)arow * DIM + kg * 8;
  const ushort* Ar2 = A2 + (size_t)arow * DIM + kg * 8;

  // prefetch all A fragments (8 loads in flight across staging)
  bf16x8 a[2][4];
#pragma unroll
  for (int ks = 0; ks < 4; ks++)
    a[0][ks] = aok ? *(const bf16x8*)(Ar1 + ks * 32)
                   : (bf16x8){0, 0, 0, 0, 0, 0, 0, 0};
#pragma unroll
  for (int ks = 0; ks < 4; ks++)
    a[1][ks] = aok ? *(const bf16x8*)(Ar2 + ks * 32)
                   : (bf16x8){0, 0, 0, 0, 0, 0, 0, 0};

  // stage both matrices: pure linear 16B copy, coalesced + conflict-free
#pragma unroll
  for (int i = 0; i < 8; i++) {
    int phys = i * 512 + tid;
    int half = phys >> 11;           // 0: W_l, 1: W_r
    int ph = phys & 2047;
    ((uint4*)Bs)[phys] = ((const uint4*)(half ? B2t : B1t))[ph];
  }
  __syncthreads();

  f32x4 acc[8];
#pragma unroll
  for (int f = 0; f < 8; f++) acc[f] = (f32x4){0.f, 0.f, 0.f, 0.f};

#pragma unroll
  for (int half = 0; half < 2; half++) {
#pragma unroll
    for (int ks = 0; ks < 4; ks++) {
#pragma unroll
      for (int f = 0; f < 8; f++) {
        bf16x8 b = *(const bf16x8*)&Bs[half][(ks * 512 + f * 64 + lane) * 8];
        acc[f] = __builtin_amdgcn_mfma_f32_16x16x32_bf16(a[half][ks], b, acc[f],
                                                         0, 0, 0);
      }
    }
  }

  if (MODE == 0) {
    ushort* O = (ushort*)outp;
#pragma unroll
    for (int rr = 0; rr < 4; rr++) {
      int orow = row0 + kg * 4 + rr;
      if (orow < NN) {
#pragma unroll
        for (int f = 0; f < 8; f++) {
          int n = f * 16 + r;
          float h = fmaxf(acc[f][rr] + bias[n], 0.f);
          O[(size_t)orow * DIM + n] = f2b(h);
        }
      }
    }
  } else {
    float* O = (float*)outp;
    float bpv = bp[0], bdv = bd[0];
#pragma unroll
    for (int rr = 0; rr < 4; rr++) {
      float p = 0.f, dv = 0.f;
#pragma unroll
      for (int f = 0; f < 8; f++) {
        int n = f * 16 + r;
        float h = fmaxf(acc[f][rr] + bias[n], 0.f);
        p += h * Wp[n];
        dv += h * Wd[n];
      }
#pragma unroll
      for (int m = 1; m < 16; m <<= 1) {
        p += __shfl_xor(p, m, 64);
        dv += __shfl_xor(dv, m, 64);
      }
      int orow = row0 + kg * 4 + rr;
      if (r == 0 && orow < NN) {
        float preds = p + bpv;
        float diffs = 1.f / (1.f + expf(-(dv + bdv)));
        O[orow] = preds - diffs;
        O[NN + orow] = preds + diffs;
      }
    }
  }
}

extern "C" void kernel_launch(void* const* d_in, const int* in_sizes, int n_in,
                              void* d_out, int out_size, void* d_ws, size_t ws_size,
                              hipStream_t stream) {
  const float* x   = (const float*)d_in[0];
  const void*  ei  = d_in[1];
  const float* W1l = (const float*)d_in[2];
  const float* b1  = (const float*)d_in[3];
  const float* W1r = (const float*)d_in[4];
  const float* W2l = (const float*)d_in[5];
  const float* b2  = (const float*)d_in[6];
  const float* W2r = (const float*)d_in[7];
  const float* Wp  = (const float*)d_in[8];
  const float* bp  = (const float*)d_in[9];
  const float* Wd  = (const float*)d_in[10];
  const float* bd  = (const float*)d_in[11];

  char* ws = (char*)d_ws;
  int* gcur   = (int*)(ws + OFF_GCUR);
  int* rowbeg = (int*)(ws + OFF_ROWB);
  int* rowend = (int*)(ws + OFF_ROWE);
  int* col    = (int*)(ws + OFF_COL);
  uint* tmp   = (uint*)(ws + OFF_TMP);
  ushort* WT  = (ushort*)(ws + OFF_WT);
  ushort* Xb  = (ushort*)(ws + OFF_XB);
  ushort* Hb  = (ushort*)(ws + OFF_HB);
  ushort* Mb  = (ushort*)(ws + OFF_MB);

  k_cvtall<<<12757, 256, 0, stream>>>(x, Xb, W1l, W1r, W2l, W2r, WT, gcur);
  k_bin<<<256, 256, 0, stream>>>(ei, gcur, tmp);
  k_reorder<<<NBUCK, 256, 0, stream>>>(tmp, gcur, rowbeg, rowend, col);

  // layer 1
  k_agg<<<(NN * 64 + 255) / 256, 256, 0, stream>>>(Xb, rowbeg, rowend, col, Mb);
  k_mm<0><<<(NN + 127) / 128, 512, 0, stream>>>(Mb, Xb, WT, WT + 16384, b1, Hb,
                                                nullptr, nullptr, nullptr, nullptr);
  // layer 2 + heads
  k_agg<<<(NN * 64 + 255) / 256, 256, 0, stream>>>(Hb, rowbeg, rowend, col, Mb);
  k_mm<1><<<(NN + 127) / 128, 512, 0, stream>>>(Mb, Hb, WT + 32768, WT + 49152, b2,
                                                d_out, Wp, bp, Wd, bd);
}

// Round 16
// 220.722 us; speedup vs baseline: 1.1647x; 1.0761x over previous
//
#include <hip/hip_runtime.h>
#include <math.h>

constexpr int NN  = 100000;   // nodes
constexpr int NE  = 1600000;  // edges
constexpr int DIM = 128;
constexpr int NBUCK = (NN + 255) / 256;      // 391 dst-buckets
constexpr int CAP  = 4608;                   // per-bucket segment capacity

typedef unsigned short ushort;
typedef unsigned int uint;
typedef __attribute__((ext_vector_type(8))) short bf16x8;
typedef __attribute__((ext_vector_type(4))) float f32x4;
typedef __attribute__((ext_vector_type(4))) uint uint4v;

// ---- workspace layout (bytes) ----
constexpr size_t OFF_GCUR   = 0;                          // int[NBUCK]
constexpr size_t OFF_ROWB   = 2048;                       // int[NN]
constexpr size_t OFF_ROWE   = OFF_ROWB + 400128;          // int[NN]
constexpr size_t OFF_COL    = OFF_ROWE + 400128;          // int[NBUCK*CAP]
constexpr size_t OFF_TMP    = OFF_COL  + 7206912;         // uint[NBUCK*CAP]
constexpr size_t OFF_WT     = OFF_TMP  + 7206912;         // 4 x 128x128 bf16 (phys order)
constexpr size_t OFF_XB     = OFF_WT   + 131072;          // bf16[NN*128]
constexpr size_t OFF_HB     = OFF_XB   + 25600000;        // bf16[NN*128]
constexpr size_t OFF_MB     = OFF_HB   + 25600000;        // bf16[NN*128]
// total ≈ 92.1 MB

__device__ __forceinline__ int eidx(const void* p, int is64, long long i) {
  return is64 ? (int)((const long long*)p)[i] : ((const int*)p)[i];
}

__device__ __forceinline__ ushort f2b(float f) {  // fp32 -> bf16 RNE
  uint u = __float_as_uint(f);
  return (ushort)((u + 0x7FFFu + ((u >> 16) & 1u)) >> 16);
}
__device__ __forceinline__ float blo(uint u) { return __uint_as_float(u << 16); }
__device__ __forceinline__ float bhi(uint u) { return __uint_as_float(u & 0xFFFF0000u); }

// block-uniform int64-vs-int32 detect (deterministic across blocks)
__device__ __forceinline__ int detect64(const void* e) {
  __shared__ int f;
  if (threadIdx.x == 0) f = 0;
  __syncthreads();
  const uint* u = (const uint*)e;
  uint v = 0;
  for (int i = threadIdx.x; i < 4096; i += blockDim.x) v |= u[2 * i + 1];
  if (v) atomicOr(&f, 1);
  __syncthreads();
  return f == 0;  // all-high-words-zero -> int64
}

// LDS multisplit: group edges by dst-bucket into tmp with full-line flushes.
// packed entry = (src << 8) | (dst & 255). 1024-edge chunks (4 coalesced
// passes) per barrier+flush cycle -> 4x fewer barriers/scans than 256-edge.
__global__ __launch_bounds__(256) void k_bin(const void* e, int* gcur,
                                             uint* tmp) {
  __shared__ uint buf[NBUCK * 32];
  __shared__ int cnt[NBUCK];
  int is64 = detect64(e);
  for (int b = threadIdx.x; b < NBUCK; b += 256) cnt[b] = 0;
  __syncthreads();

  for (int base = blockIdx.x * 1024; base < NE; base += gridDim.x * 1024) {
#pragma unroll
    for (int s = 0; s < 4; s++) {
      int i = base + s * 256 + threadIdx.x;
      if (i < NE) {
        int src = eidx(e, is64, i);
        int dst = eidx(e, is64, (long long)NE + i);
        int b = dst >> 8;
        uint pack = ((uint)src << 8) | (uint)(dst & 255);
        int c = atomicAdd(&cnt[b], 1);
        if (c < 32) {
          buf[b * 32 + c] = pack;
        } else {  // overflow (pathological skew) - direct fragmented store
          int p = atomicAdd(&gcur[b], 1);
          tmp[p] = pack;
        }
      }
    }
    __syncthreads();
    // flush full 64B lines, one thread per bucket
    for (int b = threadIdx.x; b < NBUCK; b += 256) {
      int c = min(cnt[b], 32);
      if (c >= 16) {
        int gpos = atomicAdd(&gcur[b], 16);
        uint* s = &buf[b * 32];
#pragma unroll
        for (int q = 0; q < 4; q++) {
          uint4 v = {s[q * 4 + 0], s[q * 4 + 1], s[q * 4 + 2], s[q * 4 + 3]};
          *(uint4*)(tmp + gpos + q * 4) = v;
        }
        int rem = c - 16;
        for (int q = 0; q < rem; q++) s[q] = s[16 + q];
        cnt[b] = rem;
      } else {
        cnt[b] = c;
      }
    }
    __syncthreads();
  }
  // final residual flush
  for (int b = threadIdx.x; b < NBUCK; b += 256) {
    int c = cnt[b];
    if (c > 0) {
      int gpos = atomicAdd(&gcur[b], c);
      for (int q = 0; q < c; q++) tmp[gpos + q] = buf[b * 32 + q];
    }
  }
}

// one workgroup per bucket: count node degrees from tmp segment, block-scan
// into rowbeg/rowend (coalesced), then order tmp into final col layout.
__global__ __launch_bounds__(256) void k_reorder(const uint* __restrict__ tmp,
                                                 const int* __restrict__ gcur,
                                                 int* __restrict__ rowbeg,
                                                 int* __restrict__ rowend,
                                                 int* __restrict__ col) {
  __shared__ int cnt[256];
  __shared__ int lcur[256];
  __shared__ int wsum[4];
  int b = blockIdx.x;
  int t = threadIdx.x;
  int segBeg = b * CAP;
  int segEnd = gcur[b];
  cnt[t] = 0;
  __syncthreads();
  // pass A: degree count
  for (int j = segBeg + t; j < segEnd; j += 256)
    atomicAdd(&cnt[tmp[j] & 255], 1);
  __syncthreads();
  // block exclusive scan of 256 counts
  int c = cnt[t];
  int lane = t & 63, wid = t >> 6;
  int s = c;
#pragma unroll
  for (int off = 1; off < 64; off <<= 1) {
    int v = __shfl_up(s, off, 64);
    if (lane >= off) s += v;
  }
  if (lane == 63) wsum[wid] = s;
  __syncthreads();
  if (t == 0) {
    int r0 = wsum[0], r1 = wsum[1], r2 = wsum[2];
    wsum[1] = r0;
    wsum[2] = r0 + r1;
    wsum[3] = r0 + r1 + r2;
    wsum[0] = 0;
  }
  __syncthreads();
  int excl = s - c + wsum[wid];
  int node = (b << 8) + t;
  if (node < NN) {
    rowbeg[node] = segBeg + excl;
    rowend[node] = segBeg + excl + c;
  }
  lcur[t] = segBeg + excl;
  __syncthreads();
  // pass B: scatter into col
  for (int j = segBeg + t; j < segEnd; j += 256) {
    uint p = tmp[j];
    int pos = atomicAdd(&lcur[p & 255], 1);
    col[pos] = (int)(p >> 8);
  }
}

// x fp32 -> bf16 (blocks 0..12499), weight cvt into PHYS-LINEAR layout
// (12500..12755), gcur seed (block 12756).
// phys layout (per matrix, 2048 16B-chunks): chunk = ks*512 + f*64 + kg*16 + r,
// element e: holds W[k][n] with n = f*16+r, k = (ks*4+kg)*8 + e. k_mm then
// stages LDS with a pure linear copy (coalesced + conflict-free).
__global__ void k_cvtall(const float* __restrict__ x, ushort* __restrict__ xb,
                         const float* __restrict__ W1l, const float* __restrict__ W1r,
                         const float* __restrict__ W2l, const float* __restrict__ W2r,
                         ushort* __restrict__ WT, int* __restrict__ gcur) {
  int b = blockIdx.x;
  if (b < 12500) {
    int i = b * 256 + threadIdx.x;  // one float4 each
    float4 v = ((const float4*)x)[i];
    ushort4 o = {f2b(v.x), f2b(v.y), f2b(v.z), f2b(v.w)};
    ((ushort4*)xb)[i] = o;
  } else if (b < 12756) {
    int id = (b - 12500) * 256 + threadIdx.x;  // 65536 total
    int m = id >> 14;        // matrix 0..3
    int h = id & 16383;      // halfword index within matrix (phys*8 + e)
    int e = h & 7;
    int phys = h >> 3;
    int r = phys & 15, kg = (phys >> 4) & 3;
    int f = (phys >> 6) & 7, ks = phys >> 9;
    int n = f * 16 + r;
    int k = (ks * 4 + kg) * 8 + e;
    const float* W = (m == 0) ? W1l : (m == 1) ? W1r : (m == 2) ? W2l : W2r;
    WT[m * 16384 + h] = f2b(W[k * 128 + n]);
  } else {
    for (int i = threadIdx.x; i < NBUCK; i += 256) gcur[i] = i * CAP;
  }
}

#define ACC8(P, U)                                         \
  P[0] += blo(U.x); P[1] += bhi(U.x);                      \
  P[2] += blo(U.y); P[3] += bhi(U.y);                      \
  P[4] += blo(U.z); P[5] += bhi(U.z);                      \
  P[6] += blo(U.w); P[7] += bhi(U.w);

// One wave per node. uint4-per-lane: 16 lanes cover a 256B row, 4 edge-groups
// process 4 edges per load instruction. Tail handled by one predicated
// 4-load step (clamped index + select-to-zero) -> always 4 loads deep.
__global__ void k_agg(const ushort* __restrict__ feat,
                      const int* __restrict__ rowbeg,
                      const int* __restrict__ rowend,
                      const int* __restrict__ col,
                      ushort* __restrict__ out) {
  int gtid = blockIdx.x * blockDim.x + threadIdx.x;
  int v = gtid >> 6;
  int lane = gtid & 63;
  if (v >= NN) return;
  int beg = rowbeg[v], end = rowend[v];
  int g = lane >> 4;   // edge group 0..3
  int q = lane & 15;   // 16B slot within row
  const uint4v* F4 = (const uint4v*)feat;
  float p[8] = {0.f, 0.f, 0.f, 0.f, 0.f, 0.f, 0.f, 0.f};
  int j = beg;
  for (; j + 15 < end; j += 16) {  // 4 independent 1KB loads in flight
    int c0 = __builtin_nontemporal_load(&col[j + g]);
    int c1 = __builtin_nontemporal_load(&col[j + 4 + g]);
    int c2 = __builtin_nontemporal_load(&col[j + 8 + g]);
    int c3 = __builtin_nontemporal_load(&col[j + 12 + g]);
    uint4v u0 = F4[(size_t)c0 * 16 + q];
    uint4v u1 = F4[(size_t)c1 * 16 + q];
    uint4v u2 = F4[(size_t)c2 * 16 + q];
    uint4v u3 = F4[(size_t)c3 * 16 + q];
    ACC8(p, u0)
    ACC8(p, u1)
    ACC8(p, u2)
    ACC8(p, u3)
  }
  if (j < end) {  // predicated tail: up to 15 edges, still 4 loads deep
    int last = end - 1;
    int i0 = j + g, i1 = j + 4 + g, i2 = j + 8 + g, i3 = j + 12 + g;
    int c0 = __builtin_nontemporal_load(&col[min(i0, last)]);
    int c1 = __builtin_nontemporal_load(&col[min(i1, last)]);
    int c2 = __builtin_nontemporal_load(&col[min(i2, last)]);
    int c3 = __builtin_nontemporal_load(&col[min(i3, last)]);
    uint4v u0 = F4[(size_t)c0 * 16 + q];
    uint4v u1 = F4[(size_t)c1 * 16 + q];
    uint4v u2 = F4[(size_t)c2 * 16 + q];
    uint4v u3 = F4[(size_t)c3 * 16 + q];
    uint4v z = {0, 0, 0, 0};
    if (i0 > last) u0 = z;
    if (i1 > last) u1 = z;
    if (i2 > last) u2 = z;
    if (i3 > last) u3 = z;
    ACC8(p, u0)
    ACC8(p, u1)
    ACC8(p, u2)
    ACC8(p, u3)
  }
  // reduce across the 4 groups
#pragma unroll
  for (int k = 0; k < 8; k++) {
    p[k] += __shfl_xor(p[k], 16, 64);
    p[k] += __shfl_xor(p[k], 32, 64);
  }
  float inv = 1.0f / (float)max(end - beg, 1);
  if (g == 0) {
    uint4v o;
    o.x = (uint)f2b(p[0] * inv) | ((uint)f2b(p[1] * inv) << 16);
    o.y = (uint)f2b(p[2] * inv) | ((uint)f2b(p[3] * inv) << 16);
    o.z = (uint)f2b(p[4] * inv) | ((uint)f2b(p[5] * inv) << 16);
    o.w = (uint)f2b(p[6] * inv) | ((uint)f2b(p[7] * inv) << 16);
    __builtin_nontemporal_store(o, &((uint4v*)out)[(size_t)v * 16 + q]);
  }
}

// MFMA GEMM: 128-row blocks, 8 waves, BOTH W matrices staged into 64KB LDS
// via pure linear copy (WT already in phys order), single barrier, then
// barrier-free MFMA + epilogue per wave.
template <int MODE>
__global__ __launch_bounds__(512) void k_mm(
    const ushort* __restrict__ A1, const ushort* __restrict__ A2,
    const ushort* __restrict__ B1t, const ushort* __restrict__ B2t,
    const float* __restrict__ bias, void* __restrict__ outp,
    const float* __restrict__ Wp, const float* __restrict__ bp,
    const float* __restrict__ Wd, const float* __restrict__ bd) {
  __shared__ ushort Bs[2][128 * 128];  // 64KB
  int tid = threadIdx.x;
  int wid = tid >> 6, lane = tid & 63;
  int row0 = blockIdx.x * 128 + wid * 16;
  int r = lane & 15, kg = lane >> 4;

  int arow = row0 + r;
  bool aok = arow < NN;
  const ushort* Ar1 = A1 + (size_t)arow * DIM + kg * 8;
  const ushort* Ar2 = A2 + (size_t)arow * DIM + kg * 8;

  // prefetch all A fragments (8 loads in flight across staging)
  bf16x8 a[2][4];
#pragma unroll
  for (int ks = 0; ks < 4; ks++)
    a[0][ks] = aok ? *(const bf16x8*)(Ar1 + ks * 32)
                   : (bf16x8){0, 0, 0, 0, 0, 0, 0, 0};
#pragma unroll
  for (int ks = 0; ks < 4; ks++)
    a[1][ks] = aok ? *(const bf16x8*)(Ar2 + ks * 32)
                   : (bf16x8){0, 0, 0, 0, 0, 0, 0, 0};

  // stage both matrices: pure linear 16B copy, coalesced + conflict-free
#pragma unroll
  for (int i = 0; i < 8; i++) {
    int phys = i * 512 + tid;
    int half = phys >> 11;           // 0: W_l, 1: W_r
    int ph = phys & 2047;
    ((uint4*)Bs)[phys] = ((const uint4*)(half ? B2t : B1t))[ph];
  }
  __syncthreads();

  f32x4 acc[8];
#pragma unroll
  for (int f = 0; f < 8; f++) acc[f] = (f32x4){0.f, 0.f, 0.f, 0.f};

#pragma unroll
  for (int half = 0; half < 2; half++) {
#pragma unroll
    for (int ks = 0; ks < 4; ks++) {
#pragma unroll
      for (int f = 0; f < 8; f++) {
        bf16x8 b = *(const bf16x8*)&Bs[half][(ks * 512 + f * 64 + lane) * 8];
        acc[f] = __builtin_amdgcn_mfma_f32_16x16x32_bf16(a[half][ks], b, acc[f],
                                                         0, 0, 0);
      }
    }
  }

  if (MODE == 0) {
    ushort* O = (ushort*)outp;
#pragma unroll
    for (int rr = 0; rr < 4; rr++) {
      int orow = row0 + kg * 4 + rr;
      if (orow < NN) {
#pragma unroll
        for (int f = 0; f < 8; f++) {
          int n = f * 16 + r;
          float h = fmaxf(acc[f][rr] + bias[n], 0.f);
          O[(size_t)orow * DIM + n] = f2b(h);
        }
      }
    }
  } else {
    float* O = (float*)outp;
    float bpv = bp[0], bdv = bd[0];
#pragma unroll
    for (int rr = 0; rr < 4; rr++) {
      float p = 0.f, dv = 0.f;
#pragma unroll
      for (int f = 0; f < 8; f++) {
        int n = f * 16 + r;
        float h = fmaxf(acc[f][rr] + bias[n], 0.f);
        p += h * Wp[n];
        dv += h * Wd[n];
      }
#pragma unroll
      for (int m = 1; m < 16; m <<= 1) {
        p += __shfl_xor(p, m, 64);
        dv += __shfl_xor(dv, m, 64);
      }
      int orow = row0 + kg * 4 + rr;
      if (r == 0 && orow < NN) {
        float preds = p + bpv;
        float diffs = 1.f / (1.f + expf(-(dv + bdv)));
        O[orow] = preds - diffs;
        O[NN + orow] = preds + diffs;
      }
    }
  }
}

extern "C" void kernel_launch(void* const* d_in, const int* in_sizes, int n_in,
                              void* d_out, int out_size, void* d_ws, size_t ws_size,
                              hipStream_t stream) {
  const float* x   = (const float*)d_in[0];
  const void*  ei  = d_in[1];
  const float* W1l = (const float*)d_in[2];
  const float* b1  = (const float*)d_in[3];
  const float* W1r = (const float*)d_in[4];
  const float* W2l = (const float*)d_in[5];
  const float* b2  = (const float*)d_in[6];
  const float* W2r = (const float*)d_in[7];
  const float* Wp  = (const float*)d_in[8];
  const float* bp  = (const float*)d_in[9];
  const float* Wd  = (const float*)d_in[10];
  const float* bd  = (const float*)d_in[11];

  char* ws = (char*)d_ws;
  int* gcur   = (int*)(ws + OFF_GCUR);
  int* rowbeg = (int*)(ws + OFF_ROWB);
  int* rowend = (int*)(ws + OFF_ROWE);
  int* col    = (int*)(ws + OFF_COL);
  uint* tmp   = (uint*)(ws + OFF_TMP);
  ushort* WT  = (ushort*)(ws + OFF_WT);
  ushort* Xb  = (ushort*)(ws + OFF_XB);
  ushort* Hb  = (ushort*)(ws + OFF_HB);
  ushort* Mb  = (ushort*)(ws + OFF_MB);

  k_cvtall<<<12757, 256, 0, stream>>>(x, Xb, W1l, W1r, W2l, W2r, WT, gcur);
  k_bin<<<256, 256, 0, stream>>>(ei, gcur, tmp);
  k_reorder<<<NBUCK, 256, 0, stream>>>(tmp, gcur, rowbeg, rowend, col);

  // layer 1
  k_agg<<<(NN * 64 + 255) / 256, 256, 0, stream>>>(Xb, rowbeg, rowend, col, Mb);
  k_mm<0><<<(NN + 127) / 128, 512, 0, stream>>>(Mb, Xb, WT, WT + 16384, b1, Hb,
                                                nullptr, nullptr, nullptr, nullptr);
  // layer 2 + heads
  k_agg<<<(NN * 64 + 255) / 256, 256, 0, stream>>>(Hb, rowbeg, rowend, col, Mb);
  k_mm<1><<<(NN + 127) / 128, 512, 0, stream>>>(Mb, Hb, WT + 32768, WT + 49152, b2,
                                                d_out, Wp, bp, Wd, bd);
}

// Round 17
// 216.709 us; speedup vs baseline: 1.1863x; 1.0185x over previous
//
#include <hip/hip_runtime.h>
#include <math.h>

constexpr int NN  = 100000;   // nodes
constexpr int NE  = 1600000;  // edges
constexpr int DIM = 128;
constexpr int NBUCK = (NN + 255) / 256;      // 391 dst-buckets
constexpr int CAP  = 4608;                   // per-bucket segment capacity

typedef unsigned short ushort;
typedef unsigned int uint;
typedef __attribute__((ext_vector_type(8))) short bf16x8;
typedef __attribute__((ext_vector_type(4))) float f32x4;
typedef __attribute__((ext_vector_type(4))) uint uint4v;

// ---- workspace layout (bytes) ----
constexpr size_t OFF_RCNT   = 0;                          // int[NBUCK] (relative counts)
constexpr size_t OFF_ROWB   = 2048;                       // int[NN]
constexpr size_t OFF_ROWE   = OFF_ROWB + 400128;          // int[NN]
constexpr size_t OFF_COL    = OFF_ROWE + 400128;          // int[NBUCK*CAP]
constexpr size_t OFF_TMP    = OFF_COL  + 7206912;         // uint[NBUCK*CAP]
constexpr size_t OFF_WT     = OFF_TMP  + 7206912;         // 4 x 128x128 bf16 (phys order)
constexpr size_t OFF_XB     = OFF_WT   + 131072;          // bf16[NN*128]
constexpr size_t OFF_HB     = OFF_XB   + 25600000;        // bf16[NN*128]
constexpr size_t OFF_MB     = OFF_HB   + 25600000;        // bf16[NN*128]
// total ≈ 92.1 MB

__device__ __forceinline__ int eidx(const void* p, int is64, long long i) {
  return is64 ? (int)((const long long*)p)[i] : ((const int*)p)[i];
}

__device__ __forceinline__ ushort f2b(float f) {  // fp32 -> bf16 RNE
  uint u = __float_as_uint(f);
  return (ushort)((u + 0x7FFFu + ((u >> 16) & 1u)) >> 16);
}
__device__ __forceinline__ float blo(uint u) { return __uint_as_float(u << 16); }
__device__ __forceinline__ float bhi(uint u) { return __uint_as_float(u & 0xFFFF0000u); }

// block-uniform int64-vs-int32 detect (deterministic across blocks)
__device__ __forceinline__ int detect64(const void* e, int* f) {
  if (threadIdx.x == 0) *f = 0;
  __syncthreads();
  const uint* u = (const uint*)e;
  uint v = 0;
  for (int i = threadIdx.x; i < 4096; i += blockDim.x) v |= u[2 * i + 1];
  if (v) atomicOr(f, 1);
  __syncthreads();
  return *f == 0;  // all-high-words-zero -> int64
}

// Fused prep kernel.
// Blocks 0..255: LDS multisplit of edges by dst-bucket into tmp (full-line
//   flushes, RELATIVE per-bucket cursors: tmp idx = b*CAP + rcnt). rcnt is
//   zeroed by memset before launch.
// Blocks 256..12755: x fp32 -> bf16 (float4 per thread).
// Blocks 12756..13011: weight cvt into PHYS-LINEAR layout: per matrix, 16B
//   chunk = ks*512 + f*64 + kg*16 + r; element e holds W[k][n], n = f*16+r,
//   k = (ks*4+kg)*8 + e. k_mm stages LDS with a pure linear copy.
__global__ __launch_bounds__(256) void k_prep(
    const void* e, int* rcnt, uint* tmp,
    const float* __restrict__ x, ushort* __restrict__ xb,
    const float* __restrict__ W1l, const float* __restrict__ W1r,
    const float* __restrict__ W2l, const float* __restrict__ W2r,
    ushort* __restrict__ WT) {
  __shared__ uint buf[NBUCK * 32];
  __shared__ int cnt[NBUCK];
  __shared__ int dflag;
  int blk = blockIdx.x;
  if (blk >= 256) {
    int b2 = blk - 256;
    if (b2 < 12500) {
      int i = b2 * 256 + threadIdx.x;  // one float4 each
      float4 v = ((const float4*)x)[i];
      ushort4 o = {f2b(v.x), f2b(v.y), f2b(v.z), f2b(v.w)};
      ((ushort4*)xb)[i] = o;
    } else {
      int id = (b2 - 12500) * 256 + threadIdx.x;  // 65536 total
      int m = id >> 14;        // matrix 0..3
      int h = id & 16383;      // halfword index within matrix
      int el = h & 7;
      int phys = h >> 3;
      int r = phys & 15, kg = (phys >> 4) & 3;
      int f = (phys >> 6) & 7, ks = phys >> 9;
      int n = f * 16 + r;
      int k = (ks * 4 + kg) * 8 + el;
      const float* W = (m == 0) ? W1l : (m == 1) ? W1r : (m == 2) ? W2l : W2r;
      WT[m * 16384 + h] = f2b(W[k * 128 + n]);
    }
    return;
  }

  // ---- bin role ----
  int is64 = detect64(e, &dflag);
  for (int b = threadIdx.x; b < NBUCK; b += 256) cnt[b] = 0;
  __syncthreads();

  for (int base = blk * 1024; base < NE; base += 256 * 1024) {
#pragma unroll
    for (int s = 0; s < 4; s++) {
      int i = base + s * 256 + threadIdx.x;
      if (i < NE) {
        int src = eidx(e, is64, i);
        int dst = eidx(e, is64, (long long)NE + i);
        int b = dst >> 8;
        uint pack = ((uint)src << 8) | (uint)(dst & 255);
        int c = atomicAdd(&cnt[b], 1);
        if (c < 32) {
          buf[b * 32 + c] = pack;
        } else {  // overflow (pathological skew) - direct fragmented store
          int rel = atomicAdd(&rcnt[b], 1);
          tmp[b * CAP + rel] = pack;
        }
      }
    }
    __syncthreads();
    // flush full 64B lines, one thread per bucket
    for (int b = threadIdx.x; b < NBUCK; b += 256) {
      int c = min(cnt[b], 32);
      if (c >= 16) {
        int rel = atomicAdd(&rcnt[b], 16);
        uint* s = &buf[b * 32];
        uint* gp = tmp + b * CAP + rel;
#pragma unroll
        for (int q = 0; q < 4; q++) {
          uint4 v = {s[q * 4 + 0], s[q * 4 + 1], s[q * 4 + 2], s[q * 4 + 3]};
          *(uint4*)(gp + q * 4) = v;
        }
        int rem = c - 16;
        for (int q = 0; q < rem; q++) s[q] = s[16 + q];
        cnt[b] = rem;
      } else {
        cnt[b] = c;
      }
    }
    __syncthreads();
  }
  // final residual flush
  for (int b = threadIdx.x; b < NBUCK; b += 256) {
    int c = cnt[b];
    if (c > 0) {
      int rel = atomicAdd(&rcnt[b], c);
      uint* gp = tmp + b * CAP + rel;
      for (int q = 0; q < c; q++) gp[q] = buf[b * 32 + q];
    }
  }
}

// one workgroup per bucket: count node degrees from tmp segment, block-scan
// into rowbeg/rowend (coalesced), then order tmp into final col layout.
__global__ __launch_bounds__(256) void k_reorder(const uint* __restrict__ tmp,
                                                 const int* __restrict__ rcnt,
                                                 int* __restrict__ rowbeg,
                                                 int* __restrict__ rowend,
                                                 int* __restrict__ col) {
  __shared__ int cnt[256];
  __shared__ int lcur[256];
  __shared__ int wsum[4];
  int b = blockIdx.x;
  int t = threadIdx.x;
  int segBeg = b * CAP;
  int segEnd = segBeg + rcnt[b];
  cnt[t] = 0;
  __syncthreads();
  // pass A: degree count
  for (int j = segBeg + t; j < segEnd; j += 256)
    atomicAdd(&cnt[tmp[j] & 255], 1);
  __syncthreads();
  // block exclusive scan of 256 counts
  int c = cnt[t];
  int lane = t & 63, wid = t >> 6;
  int s = c;
#pragma unroll
  for (int off = 1; off < 64; off <<= 1) {
    int v = __shfl_up(s, off, 64);
    if (lane >= off) s += v;
  }
  if (lane == 63) wsum[wid] = s;
  __syncthreads();
  if (t == 0) {
    int r0 = wsum[0], r1 = wsum[1], r2 = wsum[2];
    wsum[1] = r0;
    wsum[2] = r0 + r1;
    wsum[3] = r0 + r1 + r2;
    wsum[0] = 0;
  }
  __syncthreads();
  int excl = s - c + wsum[wid];
  int node = (b << 8) + t;
  if (node < NN) {
    rowbeg[node] = segBeg + excl;
    rowend[node] = segBeg + excl + c;
  }
  lcur[t] = segBeg + excl;
  __syncthreads();
  // pass B: scatter into col
  for (int j = segBeg + t; j < segEnd; j += 256) {
    uint p = tmp[j];
    int pos = atomicAdd(&lcur[p & 255], 1);
    col[pos] = (int)(p >> 8);
  }
}

#define ACC8(P, U)                                         \
  P[0] += blo(U.x); P[1] += bhi(U.x);                      \
  P[2] += blo(U.y); P[3] += bhi(U.y);                      \
  P[4] += blo(U.z); P[5] += bhi(U.z);                      \
  P[6] += blo(U.w); P[7] += bhi(U.w);

// One wave per node. uint4-per-lane: 16 lanes cover a 256B row, 4 edge-groups
// process 4 edges per load instruction. Tail handled by one predicated
// 4-load step (clamped index + select-to-zero) -> always 4 loads deep.
__global__ void k_agg(const ushort* __restrict__ feat,
                      const int* __restrict__ rowbeg,
                      const int* __restrict__ rowend,
                      const int* __restrict__ col,
                      ushort* __restrict__ out) {
  int gtid = blockIdx.x * blockDim.x + threadIdx.x;
  int v = gtid >> 6;
  int lane = gtid & 63;
  if (v >= NN) return;
  int beg = rowbeg[v], end = rowend[v];
  int g = lane >> 4;   // edge group 0..3
  int q = lane & 15;   // 16B slot within row
  const uint4v* F4 = (const uint4v*)feat;
  float p[8] = {0.f, 0.f, 0.f, 0.f, 0.f, 0.f, 0.f, 0.f};
  int j = beg;
  for (; j + 15 < end; j += 16) {  // 4 independent 1KB loads in flight
    int c0 = __builtin_nontemporal_load(&col[j + g]);
    int c1 = __builtin_nontemporal_load(&col[j + 4 + g]);
    int c2 = __builtin_nontemporal_load(&col[j + 8 + g]);
    int c3 = __builtin_nontemporal_load(&col[j + 12 + g]);
    uint4v u0 = F4[(size_t)c0 * 16 + q];
    uint4v u1 = F4[(size_t)c1 * 16 + q];
    uint4v u2 = F4[(size_t)c2 * 16 + q];
    uint4v u3 = F4[(size_t)c3 * 16 + q];
    ACC8(p, u0)
    ACC8(p, u1)
    ACC8(p, u2)
    ACC8(p, u3)
  }
  if (j < end) {  // predicated tail: up to 15 edges, still 4 loads deep
    int last = end - 1;
    int i0 = j + g, i1 = j + 4 + g, i2 = j + 8 + g, i3 = j + 12 + g;
    int c0 = __builtin_nontemporal_load(&col[min(i0, last)]);
    int c1 = __builtin_nontemporal_load(&col[min(i1, last)]);
    int c2 = __builtin_nontemporal_load(&col[min(i2, last)]);
    int c3 = __builtin_nontemporal_load(&col[min(i3, last)]);
    uint4v u0 = F4[(size_t)c0 * 16 + q];
    uint4v u1 = F4[(size_t)c1 * 16 + q];
    uint4v u2 = F4[(size_t)c2 * 16 + q];
    uint4v u3 = F4[(size_t)c3 * 16 + q];
    uint4v z = {0, 0, 0, 0};
    if (i0 > last) u0 = z;
    if (i1 > last) u1 = z;
    if (i2 > last) u2 = z;
    if (i3 > last) u3 = z;
    ACC8(p, u0)
    ACC8(p, u1)
    ACC8(p, u2)
    ACC8(p, u3)
  }
  // reduce across the 4 groups
#pragma unroll
  for (int k = 0; k < 8; k++) {
    p[k] += __shfl_xor(p[k], 16, 64);
    p[k] += __shfl_xor(p[k], 32, 64);
  }
  float inv = 1.0f / (float)max(end - beg, 1);
  if (g == 0) {
    uint4v o;
    o.x = (uint)f2b(p[0] * inv) | ((uint)f2b(p[1] * inv) << 16);
    o.y = (uint)f2b(p[2] * inv) | ((uint)f2b(p[3] * inv) << 16);
    o.z = (uint)f2b(p[4] * inv) | ((uint)f2b(p[5] * inv) << 16);
    o.w = (uint)f2b(p[6] * inv) | ((uint)f2b(p[7] * inv) << 16);
    __builtin_nontemporal_store(o, &((uint4v*)out)[(size_t)v * 16 + q]);
  }
}

// MFMA GEMM: 128-row blocks, 8 waves, BOTH W matrices staged into 64KB LDS
// via pure linear copy (WT already in phys order), single barrier, then
// barrier-free MFMA + epilogue per wave.
template <int MODE>
__global__ __launch_bounds__(512) void k_mm(
    const ushort* __restrict__ A1, const ushort* __restrict__ A2,
    const ushort* __restrict__ B1t, const ushort* __restrict__ B2t,
    const float* __restrict__ bias, void* __restrict__ outp,
    const float* __restrict__ Wp, const float* __restrict__ bp,
    const float* __restrict__ Wd, const float* __restrict__ bd) {
  __shared__ ushort Bs[2][128 * 128];  // 64KB
  int tid = threadIdx.x;
  int wid = tid >> 6, lane = tid & 63;
  int row0 = blockIdx.x * 128 + wid * 16;
  int r = lane & 15, kg = lane >> 4;

  int arow = row0 + r;
  bool aok = arow < NN;
  const ushort* Ar1 = A1 + (size_t)arow * DIM + kg * 8;
  const ushort* Ar2 = A2 + (size_t)arow * DIM + kg * 8;

  // prefetch all A fragments (8 loads in flight across staging)
  bf16x8 a[2][4];
#pragma unroll
  for (int ks = 0; ks < 4; ks++)
    a[0][ks] = aok ? *(const bf16x8*)(Ar1 + ks * 32)
                   : (bf16x8){0, 0, 0, 0, 0, 0, 0, 0};
#pragma unroll
  for (int ks = 0; ks < 4; ks++)
    a[1][ks] = aok ? *(const bf16x8*)(Ar2 + ks * 32)
                   : (bf16x8){0, 0, 0, 0, 0, 0, 0, 0};

  // stage both matrices: pure linear 16B copy, coalesced + conflict-free
#pragma unroll
  for (int i = 0; i < 8; i++) {
    int phys = i * 512 + tid;
    int half = phys >> 11;           // 0: W_l, 1: W_r
    int ph = phys & 2047;
    ((uint4*)Bs)[phys] = ((const uint4*)(half ? B2t : B1t))[ph];
  }
  __syncthreads();

  f32x4 acc[8];
#pragma unroll
  for (int f = 0; f < 8; f++) acc[f] = (f32x4){0.f, 0.f, 0.f, 0.f};

#pragma unroll
  for (int half = 0; half < 2; half++) {
#pragma unroll
    for (int ks = 0; ks < 4; ks++) {
#pragma unroll
      for (int f = 0; f < 8; f++) {
        bf16x8 b = *(const bf16x8*)&Bs[half][(ks * 512 + f * 64 + lane) * 8];
        acc[f] = __builtin_amdgcn_mfma_f32_16x16x32_bf16(a[half][ks], b, acc[f],
                                                         0, 0, 0);
      }
    }
  }

  if (MODE == 0) {
    ushort* O = (ushort*)outp;
#pragma unroll
    for (int rr = 0; rr < 4; rr++) {
      int orow = row0 + kg * 4 + rr;
      if (orow < NN) {
#pragma unroll
        for (int f = 0; f < 8; f++) {
          int n = f * 16 + r;
          float h = fmaxf(acc[f][rr] + bias[n], 0.f);
          O[(size_t)orow * DIM + n] = f2b(h);
        }
      }
    }
  } else {
    float* O = (float*)outp;
    float bpv = bp[0], bdv = bd[0];
#pragma unroll
    for (int rr = 0; rr < 4; rr++) {
      float p = 0.f, dv = 0.f;
#pragma unroll
      for (int f = 0; f < 8; f++) {
        int n = f * 16 + r;
        float h = fmaxf(acc[f][rr] + bias[n], 0.f);
        p += h * Wp[n];
        dv += h * Wd[n];
      }
#pragma unroll
      for (int m = 1; m < 16; m <<= 1) {
        p += __shfl_xor(p, m, 64);
        dv += __shfl_xor(dv, m, 64);
      }
      int orow = row0 + kg * 4 + rr;
      if (r == 0 && orow < NN) {
        float preds = p + bpv;
        float diffs = 1.f / (1.f + expf(-(dv + bdv)));
        O[orow] = preds - diffs;
        O[NN + orow] = preds + diffs;
      }
    }
  }
}

extern "C" void kernel_launch(void* const* d_in, const int* in_sizes, int n_in,
                              void* d_out, int out_size, void* d_ws, size_t ws_size,
                              hipStream_t stream) {
  const float* x   = (const float*)d_in[0];
  const void*  ei  = d_in[1];
  const float* W1l = (const float*)d_in[2];
  const float* b1  = (const float*)d_in[3];
  const float* W1r = (const float*)d_in[4];
  const float* W2l = (const float*)d_in[5];
  const float* b2  = (const float*)d_in[6];
  const float* W2r = (const float*)d_in[7];
  const float* Wp  = (const float*)d_in[8];
  const float* bp  = (const float*)d_in[9];
  const float* Wd  = (const float*)d_in[10];
  const float* bd  = (const float*)d_in[11];

  char* ws = (char*)d_ws;
  int* rcnt   = (int*)(ws + OFF_RCNT);
  int* rowbeg = (int*)(ws + OFF_ROWB);
  int* rowend = (int*)(ws + OFF_ROWE);
  int* col    = (int*)(ws + OFF_COL);
  uint* tmp   = (uint*)(ws + OFF_TMP);
  ushort* WT  = (ushort*)(ws + OFF_WT);
  ushort* Xb  = (ushort*)(ws + OFF_XB);
  ushort* Hb  = (ushort*)(ws + OFF_HB);
  ushort* Mb  = (ushort*)(ws + OFF_MB);

  (void)hipMemsetAsync(rcnt, 0, NBUCK * sizeof(int), stream);
  k_prep<<<13012, 256, 0, stream>>>(ei, rcnt, tmp, x, Xb, W1l, W1r, W2l, W2r, WT);
  k_reorder<<<NBUCK, 256, 0, stream>>>(tmp, rcnt, rowbeg, rowend, col);

  // layer 1
  k_agg<<<(NN * 64 + 255) / 256, 256, 0, stream>>>(Xb, rowbeg, rowend, col, Mb);
  k_mm<0><<<(NN + 127) / 128, 512, 0, stream>>>(Mb, Xb, WT, WT + 16384, b1, Hb,
                                                nullptr, nullptr, nullptr, nullptr);
  // layer 2 + heads
  k_agg<<<(NN * 64 + 255) / 256, 256, 0, stream>>>(Hb, rowbeg, rowend, col, Mb);
  k_mm<1><<<(NN + 127) / 128, 512, 0, stream>>>(Mb, Hb, WT + 32768, WT + 49152, b2,
                                                d_out, Wp, bp, Wd, bd);
}